// Round 7
// baseline (196.527 us; speedup 1.0000x reference)
//
#include <hip/hip_runtime.h>

#define S_LEN 2048
#define D_EMB 1024
#define H_CNT 16
#define DHD   64
#define N_QKV 3072

typedef __attribute__((ext_vector_type(8))) short short8;
typedef __attribute__((ext_vector_type(4))) float f32x4;
typedef unsigned short u16;

__device__ __forceinline__ u16 f2bf(float f) {
  unsigned u = __float_as_uint(f);
  u += 0x7FFFu + ((u >> 16) & 1u);
  return (u16)(u >> 16);
}

// packs bf16(lo) into low16, bf16(hi) into high16 (RNE)
__device__ __forceinline__ unsigned cvtpk(float lo, float hi) {
  unsigned r;
  asm("v_cvt_pk_bf16_f32 %0, %1, %2" : "=v"(r) : "v"(lo), "v"(hi));
  return r;
}

__device__ __forceinline__ void gload16(const void* g, void* lds) {
  __builtin_amdgcn_global_load_lds(
      (const __attribute__((address_space(1))) void*)g,
      (__attribute__((address_space(3))) void*)lds, 16, 0, 0);
}

// ---------------- prep: x fp32 -> bf16 (same layout) ----------------
__global__ __launch_bounds__(256) void cvt_x_kern(const float* __restrict__ x,
                                                  u16* __restrict__ xb) {
  int i = blockIdx.x * 256 + threadIdx.x;  // 1M float4s
  float4 v = ((const float4*)x)[i];
  unsigned* o = (unsigned*)&((ushort4*)xb)[i];
  o[0] = cvtpk(v.x, v.y);
  o[1] = cvtpk(v.z, v.w);
}

// ---------------- prep: W[k][c] fp32 -> Wt[c][k] bf16 ----------------
__global__ __launch_bounds__(256) void cvt_wt_kern(const float* __restrict__ w,
                                                   u16* __restrict__ wt) {
  __shared__ u16 tile[64][65];
  const int ct = blockIdx.x, kt = blockIdx.y, t = threadIdx.x;
#pragma unroll
  for (int i = 0; i < 4; ++i) {
    int idx = t + i * 256;              // 0..1023 float4s of the 64x64 tile
    int kk = idx >> 4, c4 = (idx & 15) * 4;
    float4 v = *(const float4*)(w + (size_t)(kt * 64 + kk) * N_QKV + ct * 64 + c4);
    tile[kk][c4 + 0] = f2bf(v.x);
    tile[kk][c4 + 1] = f2bf(v.y);
    tile[kk][c4 + 2] = f2bf(v.z);
    tile[kk][c4 + 3] = f2bf(v.w);
  }
  __syncthreads();
#pragma unroll
  for (int i = 0; i < 2; ++i) {
    int id = t + i * 256;               // 0..511 short8 chunks
    int c = id >> 3, k8 = (id & 7) * 8;
    short8 o;
#pragma unroll
    for (int j = 0; j < 8; ++j) o[j] = (short)tile[k8 + j][c];
    *(short8*)&wt[(size_t)(ct * 64 + c) * D_EMB + kt * 64 + k8] = o;
  }
}

// ---------------- QKV GEMM ----------------
// 128x128 tile, BK=64, 4 waves, mfma 16x16x32 bf16, single-buffer m97 structure.
// R7 bisect: ONLY change vs passing R5 = K-loop reshape (8 B-frags resident,
// A-frags loaded per-m) to cut peak live VGPRs. No launch-bounds forcing.
// q/k: C^T orientation (A=Wt,B=X); v: C orientation. Epilogue staged through LDS
// for coalesced 16B stores. q pre-scaled by 0.125*log2(e).
__global__ __launch_bounds__(256) void qkv_gemm_kern(
    const u16* __restrict__ xb, const u16* __restrict__ wt,
    const float* __restrict__ bias,
    u16* __restrict__ qo, u16* __restrict__ ko, u16* __restrict__ vo) {
  __shared__ __align__(16) u16 SM[128 * 128];     // staging: As=SM[0:8K), Bs=SM[8K:16K)
  u16* As = SM;
  u16* Bs = SM + 128 * 64;
  const int t = threadIdx.x;
  const int w = t >> 6, l = t & 63, lr = l & 15, lg = l >> 4;
  const int wr = w >> 1, wc = w & 1;
  const int row0 = blockIdx.x * 128, col0 = blockIdx.y * 128;
  const int srow = l >> 3, scol = (l & 7) * 16;
  const int tsel = col0 >> 10;                    // 0=q 1=k 2=v (uniform)
  const bool ctq = (tsel < 2);

  f32x4 acc[4][4];
#pragma unroll
  for (int m = 0; m < 4; ++m)
#pragma unroll
    for (int n = 0; n < 4; ++n) acc[m][n] = (f32x4){0.f, 0.f, 0.f, 0.f};

  const int ldrow = w * 32;                       // this wave's staging rows
  for (int ki = 0; ki < 16; ++ki) {
    int k0 = ki * 64;
#pragma unroll
    for (int c = 0; c < 4; ++c) {
      int tr = ldrow + c * 8 + srow;
      int sc = scol ^ ((tr & 7) << 4);
      gload16((const char*)xb + (size_t)(row0 + tr) * (D_EMB * 2) + k0 * 2 + sc,
              (char*)As + (ldrow + c * 8) * 128);
      gload16((const char*)wt + (size_t)(col0 + tr) * (D_EMB * 2) + k0 * 2 + sc,
              (char*)Bs + (ldrow + c * 8) * 128);
    }
    __syncthreads();
    const u16* Ab = ctq ? Bs : As;
    const u16* Bb = ctq ? As : Bs;
    const int ar0 = ctq ? wc * 64 : wr * 64;
    const int br0 = ctq ? wr * 64 : wc * 64;
    short8 bfr[4][2];
#pragma unroll
    for (int n = 0; n < 4; ++n) {
      int br = br0 + n * 16 + lr;
#pragma unroll
      for (int kk = 0; kk < 2; ++kk)
        bfr[n][kk] = *(const short8*)&Bb[(br << 6) + ((kk * 32 + lg * 8) ^ ((br & 7) << 3))];
    }
#pragma unroll
    for (int m = 0; m < 4; ++m) {
      int ar = ar0 + m * 16 + lr;
      short8 a0 = *(const short8*)&Ab[(ar << 6) + ((lg * 8) ^ ((ar & 7) << 3))];
      short8 a1 = *(const short8*)&Ab[(ar << 6) + ((32 + lg * 8) ^ ((ar & 7) << 3))];
#pragma unroll
      for (int n = 0; n < 4; ++n) {
        acc[m][n] = __builtin_amdgcn_mfma_f32_16x16x32_bf16(a0, bfr[n][0], acc[m][n], 0, 0, 0);
        acc[m][n] = __builtin_amdgcn_mfma_f32_16x16x32_bf16(a1, bfr[n][1], acc[m][n], 0, 0, 0);
      }
    }
    __syncthreads();
  }

  const int bb = row0 >> 11;                      // batch (uniform)
  if (ctq) {
    // acc[m][n][r]: qkvcol = wc*64+m*16+lg*4+r ; s_local = wr*64+n*16+lr
    // LDS tile T[s][qc] (u16, row 128), swizzled: elem qc ^ ((s&7)<<3)
    const float scl = (tsel == 0) ? (0.125f * 1.44269504f) : 1.0f;
    u16* dst = (tsel == 0) ? qo : ko;
#pragma unroll
    for (int m = 0; m < 4; ++m) {
      int qc0 = wc * 64 + m * 16 + lg * 4;
      float4 bn = *(const float4*)&bias[col0 + qc0];
#pragma unroll
      for (int n = 0; n < 4; ++n) {
        int s = wr * 64 + n * 16 + lr;
        uint2 pk;
        pk.x = cvtpk((acc[m][n][0] + bn.x) * scl, (acc[m][n][1] + bn.y) * scl);
        pk.y = cvtpk((acc[m][n][2] + bn.z) * scl, (acc[m][n][3] + bn.w) * scl);
        *(uint2*)&SM[(s << 7) + (qc0 ^ ((s & 7) << 3))] = pk;
      }
    }
    __syncthreads();
    // readout: thread (c=t&15, rl=t>>4); 8 passes of 16 s-rows
    const int c = t & 15, rl = t >> 4;
#pragma unroll
    for (int pass = 0; pass < 8; ++pass) {
      int s = pass * 16 + rl;
      short8 v = *(const short8*)&SM[(s << 7) + ((c ^ (s & 7)) << 3)];
      int d = (col0 + c * 8) & 1023, hh = d >> 6, dh = d & 63;
      *(short8*)(dst + ((size_t)(bb * H_CNT + hh) * S_LEN + (row0 & 2047) + s) * DHD + dh) = v;
    }
  } else {
    // acc[m][n][r]: s_local = wr*64+m*16+lg*4+r ; qc = wc*64+n*16+lr
    // LDS tile T[qc][s] (u16, row 128), swizzled: elem s ^ ((qc&7)<<3)
#pragma unroll
    for (int n = 0; n < 4; ++n) {
      int qc = wc * 64 + n * 16 + lr;
      float bn = bias[col0 + qc];
#pragma unroll
      for (int m = 0; m < 4; ++m) {
        int s0l = wr * 64 + m * 16 + lg * 4;
        uint2 pk;
        pk.x = cvtpk(acc[m][n][0] + bn, acc[m][n][1] + bn);
        pk.y = cvtpk(acc[m][n][2] + bn, acc[m][n][3] + bn);
        *(uint2*)&SM[(qc << 7) + (s0l ^ ((qc & 7) << 3))] = pk;
      }
    }
    __syncthreads();
    const int c = t & 15, rl = t >> 4;
#pragma unroll
    for (int pass = 0; pass < 8; ++pass) {
      int qc = pass * 16 + rl;
      short8 v = *(const short8*)&SM[(qc << 7) + ((c ^ (qc & 7)) << 3)];
      int d = (col0 + qc) & 1023, hh = d >> 6, dh = d & 63;
      *(short8*)(vo + ((size_t)(bb * H_CNT + hh) * DHD + dh) * S_LEN +
                 (row0 & 2047) + c * 8) = v;
    }
  }
}

// ---------------- flash attention (R5 structure, byte-identical logic) ----------------
// grid (32 q-tiles, 32 b*h). 4 waves x 16 q-rows. KV tiles of 64, 2-phase dbuf.
// Swapped QK^T: St = mfma(K, Q) so lane's q = lane&15 -> in-reg softmax.
// Q pre-scaled by 0.125*log2(e) -> scores directly in log2 units.
__global__ __launch_bounds__(256) void attn_kern(
    const u16* __restrict__ qp, const u16* __restrict__ kp,
    const u16* __restrict__ vtp, float* __restrict__ out) {
  __shared__ __align__(16) u16 Ks[2][64 * 64];
  __shared__ __align__(16) u16 Vs[2][64 * 64];   // Vt tile: [dh][key]
  __shared__ __align__(16) u16 Ps[4][16 * 64];
  const int t = threadIdx.x;
  const int w = t >> 6, l = t & 63, lr = l & 15, lg = l >> 4;
  const int qt = blockIdx.x, bh = blockIdx.y;
  const int b = bh >> 4, h = bh & 15;
  const int srow = l >> 3, scol = (l & 7) * 16;

  // Q fragment (B-operand: lane holds Q[q=lane&15][dh=(lane>>4)*8+e])
  const u16* qbase = qp + ((size_t)bh * S_LEN + qt * 64 + w * 16) * DHD;
  short8 qf[2];
#pragma unroll
  for (int kk = 0; kk < 2; ++kk)
    qf[kk] = *(const short8*)(qbase + lr * DHD + kk * 32 + lg * 8);

  float mrun = -__builtin_inff(), lsum = 0.f;
  f32x4 oacc[4];
#pragma unroll
  for (int ct = 0; ct < 4; ++ct) oacc[ct] = (f32x4){0.f, 0.f, 0.f, 0.f};

  const char* kt_g = (const char*)(kp + (size_t)bh * S_LEN * DHD);
  const char* vt_g = (const char*)(vtp + (size_t)bh * DHD * S_LEN);

#define ATTN_STAGE(it, buf)                                                     \
  {                                                                             \
    int kv0 = (it) * 64;                                                        \
    _Pragma("unroll") for (int c = 0; c < 2; ++c) {                             \
      int r8 = w * 16 + c * 8;                                                  \
      int row = r8 + srow;                                                      \
      int sc = scol ^ ((row & 7) << 4);                                         \
      gload16(kt_g + (size_t)(kv0 + row) * 128 + sc, (char*)Ks[buf] + r8 * 128);\
      gload16(vt_g + (size_t)row * (S_LEN * 2) + kv0 * 2 + sc,                  \
              (char*)Vs[buf] + r8 * 128);                                       \
    }                                                                           \
  }

  ATTN_STAGE(0, 0)
  __syncthreads();

  for (int it = 0; it < S_LEN / 64; ++it) {
    int cur = it & 1;
    if (it < S_LEN / 64 - 1) ATTN_STAGE(it + 1, cur ^ 1)

    // St[key][q] = K Q^T (scores already in log2 units)
    f32x4 st[4];
#pragma unroll
    for (int k2 = 0; k2 < 4; ++k2) st[k2] = (f32x4){0.f, 0.f, 0.f, 0.f};
#pragma unroll
    for (int kk = 0; kk < 2; ++kk)
#pragma unroll
      for (int k2 = 0; k2 < 4; ++k2) {
        int ar = k2 * 16 + lr;
        short8 a = *(const short8*)&Ks[cur][(ar << 6) +
                                           ((kk * 32 + lg * 8) ^ ((ar & 7) << 3))];
        st[k2] = __builtin_amdgcn_mfma_f32_16x16x32_bf16(a, qf[kk], st[k2], 0, 0, 0);
      }

    // online softmax with defer-max (per-lane q = lane&15)
    float mx = -__builtin_inff();
#pragma unroll
    for (int k2 = 0; k2 < 4; ++k2)
#pragma unroll
      for (int r = 0; r < 4; ++r) mx = fmaxf(mx, st[k2][r]);
    mx = fmaxf(mx, __shfl_xor(mx, 16, 64));
    mx = fmaxf(mx, __shfl_xor(mx, 32, 64));
    if (!__all(mx - mrun <= 8.0f)) {
      float mnew = fmaxf(mrun, mx);
      float fsc = exp2f(mrun - mnew);
      float fr[4];
#pragma unroll
      for (int r = 0; r < 4; ++r) fr[r] = __shfl(fsc, lg * 4 + r, 64);
#pragma unroll
      for (int ct = 0; ct < 4; ++ct)
#pragma unroll
        for (int r = 0; r < 4; ++r) oacc[ct][r] *= fr[r];
      lsum *= fsc;
      mrun = mnew;
    }
    float rs = 0.f;
#pragma unroll
    for (int k2 = 0; k2 < 4; ++k2) {
      float p0 = exp2f(st[k2][0] - mrun), p1 = exp2f(st[k2][1] - mrun);
      float p2 = exp2f(st[k2][2] - mrun), p3 = exp2f(st[k2][3] - mrun);
      rs += (p0 + p1) + (p2 + p3);
      int key0 = k2 * 16 + lg * 4;
      int e = key0 ^ ((lr & 7) << 3);              // pairs stay adjacent (swz bits >= 3)
      *(unsigned*)&Ps[w][(lr << 6) + e + 0] = cvtpk(p0, p1);
      *(unsigned*)&Ps[w][(lr << 6) + e + 2] = cvtpk(p2, p3);
    }
    rs += __shfl_xor(rs, 16, 64);
    rs += __shfl_xor(rs, 32, 64);
    lsum += rs;

    // PV: O += P[16q x 64key] * Vt^T
    short8 pa[2];
#pragma unroll
    for (int kk = 0; kk < 2; ++kk)
      pa[kk] = *(const short8*)&Ps[w][(lr << 6) + ((kk * 32 + lg * 8) ^ ((lr & 7) << 3))];
#pragma unroll
    for (int ct = 0; ct < 4; ++ct)
#pragma unroll
      for (int kk = 0; kk < 2; ++kk) {
        int br = ct * 16 + lr;
        short8 bv = *(const short8*)&Vs[cur][(br << 6) +
                                            ((kk * 32 + lg * 8) ^ ((br & 7) << 3))];
        oacc[ct] = __builtin_amdgcn_mfma_f32_16x16x32_bf16(pa[kk], bv, oacc[ct], 0, 0, 0);
      }
    __syncthreads();
  }

  float inv = 1.0f / lsum;
  float invr[4];
#pragma unroll
  for (int r = 0; r < 4; ++r) invr[r] = __shfl(inv, lg * 4 + r, 64);
  const int qg0 = qt * 64 + w * 16 + lg * 4;
#pragma unroll
  for (int ct = 0; ct < 4; ++ct) {
    int col = h * 64 + ct * 16 + lr;
#pragma unroll
    for (int r = 0; r < 4; ++r)
      out[((size_t)b * S_LEN + qg0 + r) * D_EMB + col] = oacc[ct][r] * invr[r];
  }
}

extern "C" void kernel_launch(void* const* d_in, const int* in_sizes, int n_in,
                              void* d_out, int out_size, void* d_ws, size_t ws_size,
                              hipStream_t stream) {
  (void)in_sizes; (void)n_in; (void)out_size; (void)ws_size;
  const float* x  = (const float*)d_in[0];
  const float* Wq = (const float*)d_in[1];
  const float* bq = (const float*)d_in[2];
  float* out = (float*)d_out;
  char* ws = (char*)d_ws;
  // workspace layout (38 MB total)
  u16* xb = (u16*)(ws);                               //  8 MB: x bf16 [4096][1024]
  u16* wt = (u16*)(ws + (size_t)8  * 1024 * 1024);    //  6 MB: Wt bf16 [3072][1024]
  u16* qb = (u16*)(ws + (size_t)14 * 1024 * 1024);    //  8 MB: q [B,H,S,Dh] (pre-scaled)
  u16* kb = (u16*)(ws + (size_t)22 * 1024 * 1024);    //  8 MB: k [B,H,S,Dh]
  u16* vb = (u16*)(ws + (size_t)30 * 1024 * 1024);    //  8 MB: Vt [B,H,Dh,S]

  cvt_x_kern <<<4096, 256, 0, stream>>>(x, xb);
  cvt_wt_kern<<<dim3(48, 16), 256, 0, stream>>>(Wq, wt);
  qkv_gemm_kern<<<dim3(32, 24), 256, 0, stream>>>(xb, wt, bq, qb, kb, vb);
  attn_kern  <<<dim3(32, 32), 256, 0, stream>>>(qb, kb, vb, out);
}

// Round 8
// 190.378 us; speedup vs baseline: 1.0323x; 1.0323x over previous
//
#include <hip/hip_runtime.h>

#define S_LEN 2048
#define D_EMB 1024
#define H_CNT 16
#define DHD   64
#define N_QKV 3072

typedef __attribute__((ext_vector_type(8))) short short8;
typedef __attribute__((ext_vector_type(4))) float f32x4;
typedef __attribute__((ext_vector_type(4))) unsigned u32x4;
typedef unsigned short u16;

__device__ __forceinline__ u16 f2bf(float f) {
  unsigned u = __float_as_uint(f);
  u += 0x7FFFu + ((u >> 16) & 1u);
  return (u16)(u >> 16);
}

// packs bf16(lo) into low16, bf16(hi) into high16 (RNE)
__device__ __forceinline__ unsigned cvtpk(float lo, float hi) {
  unsigned r;
  asm("v_cvt_pk_bf16_f32 %0, %1, %2" : "=v"(r) : "v"(lo), "v"(hi));
  return r;
}

__device__ __forceinline__ void gload16(const void* g, void* lds) {
  __builtin_amdgcn_global_load_lds(
      (const __attribute__((address_space(1))) void*)g,
      (__attribute__((address_space(3))) void*)lds, 16, 0, 0);
}

// ---------------- prep: x fp32 -> bf16 (same layout) ----------------
__global__ __launch_bounds__(256) void cvt_x_kern(const float* __restrict__ x,
                                                  u16* __restrict__ xb) {
  int i = blockIdx.x * 256 + threadIdx.x;  // 1M float4s
  float4 v = ((const float4*)x)[i];
  unsigned* o = (unsigned*)&((ushort4*)xb)[i];
  o[0] = cvtpk(v.x, v.y);
  o[1] = cvtpk(v.z, v.w);
}

// ---------------- prep: W[k][c] fp32 -> Wt[c][k] bf16 ----------------
__global__ __launch_bounds__(256) void cvt_wt_kern(const float* __restrict__ w,
                                                   u16* __restrict__ wt) {
  __shared__ u16 tile[64][65];
  const int ct = blockIdx.x, kt = blockIdx.y, t = threadIdx.x;
#pragma unroll
  for (int i = 0; i < 4; ++i) {
    int idx = t + i * 256;              // 0..1023 float4s of the 64x64 tile
    int kk = idx >> 4, c4 = (idx & 15) * 4;
    float4 v = *(const float4*)(w + (size_t)(kt * 64 + kk) * N_QKV + ct * 64 + c4);
    tile[kk][c4 + 0] = f2bf(v.x);
    tile[kk][c4 + 1] = f2bf(v.y);
    tile[kk][c4 + 2] = f2bf(v.z);
    tile[kk][c4 + 3] = f2bf(v.w);
  }
  __syncthreads();
#pragma unroll
  for (int i = 0; i < 2; ++i) {
    int id = t + i * 256;               // 0..511 short8 chunks
    int c = id >> 3, k8 = (id & 7) * 8;
    short8 o;
#pragma unroll
    for (int j = 0; j < 8; ++j) o[j] = (short)tile[k8 + j][c];
    *(short8*)&wt[(size_t)(ct * 64 + c) * D_EMB + kt * 64 + k8] = o;
  }
}

// ---------------- QKV GEMM (R7-passing version, unchanged) ----------------
__global__ __launch_bounds__(256) void qkv_gemm_kern(
    const u16* __restrict__ xb, const u16* __restrict__ wt,
    const float* __restrict__ bias,
    u16* __restrict__ qo, u16* __restrict__ ko, u16* __restrict__ vo) {
  __shared__ __align__(16) u16 SM[128 * 128];     // staging: As=SM[0:8K), Bs=SM[8K:16K)
  u16* As = SM;
  u16* Bs = SM + 128 * 64;
  const int t = threadIdx.x;
  const int w = t >> 6, l = t & 63, lr = l & 15, lg = l >> 4;
  const int wr = w >> 1, wc = w & 1;
  const int row0 = blockIdx.x * 128, col0 = blockIdx.y * 128;
  const int srow = l >> 3, scol = (l & 7) * 16;
  const int tsel = col0 >> 10;                    // 0=q 1=k 2=v (uniform)
  const bool ctq = (tsel < 2);

  f32x4 acc[4][4];
#pragma unroll
  for (int m = 0; m < 4; ++m)
#pragma unroll
    for (int n = 0; n < 4; ++n) acc[m][n] = (f32x4){0.f, 0.f, 0.f, 0.f};

  const int ldrow = w * 32;                       // this wave's staging rows
  for (int ki = 0; ki < 16; ++ki) {
    int k0 = ki * 64;
#pragma unroll
    for (int c = 0; c < 4; ++c) {
      int tr = ldrow + c * 8 + srow;
      int sc = scol ^ ((tr & 7) << 4);
      gload16((const char*)xb + (size_t)(row0 + tr) * (D_EMB * 2) + k0 * 2 + sc,
              (char*)As + (ldrow + c * 8) * 128);
      gload16((const char*)wt + (size_t)(col0 + tr) * (D_EMB * 2) + k0 * 2 + sc,
              (char*)Bs + (ldrow + c * 8) * 128);
    }
    __syncthreads();
    const u16* Ab = ctq ? Bs : As;
    const u16* Bb = ctq ? As : Bs;
    const int ar0 = ctq ? wc * 64 : wr * 64;
    const int br0 = ctq ? wr * 64 : wc * 64;
    short8 bfr[4][2];
#pragma unroll
    for (int n = 0; n < 4; ++n) {
      int br = br0 + n * 16 + lr;
#pragma unroll
      for (int kk = 0; kk < 2; ++kk)
        bfr[n][kk] = *(const short8*)&Bb[(br << 6) + ((kk * 32 + lg * 8) ^ ((br & 7) << 3))];
    }
#pragma unroll
    for (int m = 0; m < 4; ++m) {
      int ar = ar0 + m * 16 + lr;
      short8 a0 = *(const short8*)&Ab[(ar << 6) + ((lg * 8) ^ ((ar & 7) << 3))];
      short8 a1 = *(const short8*)&Ab[(ar << 6) + ((32 + lg * 8) ^ ((ar & 7) << 3))];
#pragma unroll
      for (int n = 0; n < 4; ++n) {
        acc[m][n] = __builtin_amdgcn_mfma_f32_16x16x32_bf16(a0, bfr[n][0], acc[m][n], 0, 0, 0);
        acc[m][n] = __builtin_amdgcn_mfma_f32_16x16x32_bf16(a1, bfr[n][1], acc[m][n], 0, 0, 0);
      }
    }
    __syncthreads();
  }

  const int bb = row0 >> 11;                      // batch (uniform)
  if (ctq) {
    const float scl = (tsel == 0) ? (0.125f * 1.44269504f) : 1.0f;
    u16* dst = (tsel == 0) ? qo : ko;
#pragma unroll
    for (int m = 0; m < 4; ++m) {
      int qc0 = wc * 64 + m * 16 + lg * 4;
      float4 bn = *(const float4*)&bias[col0 + qc0];
#pragma unroll
      for (int n = 0; n < 4; ++n) {
        int s = wr * 64 + n * 16 + lr;
        uint2 pk;
        pk.x = cvtpk((acc[m][n][0] + bn.x) * scl, (acc[m][n][1] + bn.y) * scl);
        pk.y = cvtpk((acc[m][n][2] + bn.z) * scl, (acc[m][n][3] + bn.w) * scl);
        *(uint2*)&SM[(s << 7) + (qc0 ^ ((s & 7) << 3))] = pk;
      }
    }
    __syncthreads();
    const int c = t & 15, rl = t >> 4;
#pragma unroll
    for (int pass = 0; pass < 8; ++pass) {
      int s = pass * 16 + rl;
      short8 v = *(const short8*)&SM[(s << 7) + ((c ^ (s & 7)) << 3)];
      int d = (col0 + c * 8) & 1023, hh = d >> 6, dh = d & 63;
      *(short8*)(dst + ((size_t)(bb * H_CNT + hh) * S_LEN + (row0 & 2047) + s) * DHD + dh) = v;
    }
  } else {
#pragma unroll
    for (int n = 0; n < 4; ++n) {
      int qc = wc * 64 + n * 16 + lr;
      float bn = bias[col0 + qc];
#pragma unroll
      for (int m = 0; m < 4; ++m) {
        int s0l = wr * 64 + m * 16 + lg * 4;
        uint2 pk;
        pk.x = cvtpk(acc[m][n][0] + bn, acc[m][n][1] + bn);
        pk.y = cvtpk(acc[m][n][2] + bn, acc[m][n][3] + bn);
        *(uint2*)&SM[(qc << 7) + (s0l ^ ((qc & 7) << 3))] = pk;
      }
    }
    __syncthreads();
    const int c = t & 15, rl = t >> 4;
#pragma unroll
    for (int pass = 0; pass < 8; ++pass) {
      int qc = pass * 16 + rl;
      short8 v = *(const short8*)&SM[(qc << 7) + ((c ^ (qc & 7)) << 3)];
      int d = (col0 + qc) & 1023, hh = d >> 6, dh = d & 63;
      *(short8*)(vo + ((size_t)(bb * H_CNT + hh) * DHD + dh) * S_LEN +
                 (row0 & 2047) + c * 8) = v;
    }
  }
}

// ---------------- flash attention ----------------
// R8 bisect: R6's in-register-P rewrite, but NO forced launch bounds.
// grid (32 q-tiles, 32 b*h). 4 waves x 16 q-rows. KV tiles of 64, 2-phase dbuf,
// unrolled x2 (buffer index compile-time -> static LDS addressing).
// Swapped QK^T: St = mfma(K, Q), lane's q = lane&15 -> in-reg softmax.
// K staged with row permutation tau so the QK^T C-layout lands exactly the keys
// each lane needs for the PV A-fragment: P never leaves registers (no LDS, no shfl).
//   LDS row j holds key tau(j) = ((j&15)>>2)*8 + ((j>>4)&1)*4 + (j&3) + (j>>5)*32
//   => score st[k2][r] is key (k2>>1)*32 + lg*8 + (k2&1)*4 + r, q = lane&15
//   => PV A-frag[kk] = cvtpk of st[2kk..2kk+1]: keys kk*32 + lg*8 + (0..7).
// Q pre-scaled by 0.125*log2(e) -> scores directly in log2 units.
__global__ __launch_bounds__(256) void attn_kern(
    const u16* __restrict__ qp, const u16* __restrict__ kp,
    const u16* __restrict__ vtp, float* __restrict__ out) {
  __shared__ __align__(16) u16 Ks[2][64 * 64];
  __shared__ __align__(16) u16 Vs[2][64 * 64];   // Vt tile: [dh][key]
  const int t = threadIdx.x;
  const int w = t >> 6, l = t & 63, lr = l & 15, lg = l >> 4;
  const int qt = blockIdx.x, bh = blockIdx.y;
  const int b = bh >> 4, h = bh & 15;
  const int srow = l >> 3, scol = (l & 7) * 16;

  // Q fragment (B-operand: lane holds Q[q=lane&15][dh=(lane>>4)*8+e])
  const u16* qbase = qp + ((size_t)bh * S_LEN + qt * 64 + w * 16) * DHD;
  short8 qf[2];
#pragma unroll
  for (int kk = 0; kk < 2; ++kk)
    qf[kk] = *(const short8*)(qbase + lr * DHD + kk * 32 + lg * 8);

  float mrun = -__builtin_inff(), lsum = 0.f;
  f32x4 oacc[4];
#pragma unroll
  for (int ct = 0; ct < 4; ++ct) oacc[ct] = (f32x4){0.f, 0.f, 0.f, 0.f};

  // per-lane loop-invariant staging source offsets
  int koff[2], voff[2];
#pragma unroll
  for (int c = 0; c < 2; ++c) {
    int row = w * 16 + c * 8 + srow;
    int sc = scol ^ ((row & 7) << 4);
    int tau = ((row & 15) >> 2) * 8 + ((row >> 4) & 1) * 4 + (row & 3) + (row >> 5) * 32;
    koff[c] = tau * 128 + sc;
    voff[c] = row * (S_LEN * 2) + sc;
  }
  const char* kpt = (const char*)(kp + (size_t)bh * S_LEN * DHD);
  const char* vpt = (const char*)(vtp + (size_t)bh * DHD * S_LEN);

#define ATTN_STAGE(BUF)                                                   \
  {                                                                       \
    _Pragma("unroll") for (int c = 0; c < 2; ++c) {                       \
      int r8 = w * 16 + c * 8;                                            \
      gload16(kpt + koff[c], (char*)Ks[BUF] + r8 * 128);                  \
      gload16(vpt + voff[c], (char*)Vs[BUF] + r8 * 128);                  \
    }                                                                     \
    kpt += 64 * 128;                                                      \
    vpt += 64 * 2;                                                        \
  }

#define ATTN_TILE(BUF, PF)                                                        \
  {                                                                               \
    if (PF) ATTN_STAGE(BUF ^ 1)                                                   \
    f32x4 st[4];                                                                  \
    _Pragma("unroll") for (int k2 = 0; k2 < 4; ++k2)                              \
        st[k2] = (f32x4){0.f, 0.f, 0.f, 0.f};                                     \
    _Pragma("unroll") for (int kk = 0; kk < 2; ++kk)                              \
      _Pragma("unroll") for (int k2 = 0; k2 < 4; ++k2) {                          \
        int ar = k2 * 16 + lr;                                                    \
        short8 a = *(const short8*)&Ks[BUF][(ar << 6) +                           \
                                            ((kk * 32 + lg * 8) ^ ((ar & 7) << 3))]; \
        st[k2] = __builtin_amdgcn_mfma_f32_16x16x32_bf16(a, qf[kk], st[k2], 0, 0, 0); \
      }                                                                           \
    float mx = fmaxf(fmaxf(fmaxf(st[0][0], st[0][1]), fmaxf(st[0][2], st[0][3])), \
                     fmaxf(fmaxf(st[1][0], st[1][1]), fmaxf(st[1][2], st[1][3]))); \
    mx = fmaxf(mx, fmaxf(fmaxf(fmaxf(st[2][0], st[2][1]), fmaxf(st[2][2], st[2][3])), \
                         fmaxf(fmaxf(st[3][0], st[3][1]), fmaxf(st[3][2], st[3][3])))); \
    mx = fmaxf(mx, __shfl_xor(mx, 16, 64));                                       \
    mx = fmaxf(mx, __shfl_xor(mx, 32, 64));                                       \
    if (!__all(mx - mrun <= 8.0f)) {                                              \
      float mnew = fmaxf(mrun, mx);                                               \
      float fsc = exp2f(mrun - mnew);                                             \
      float fr[4];                                                                \
      _Pragma("unroll") for (int r = 0; r < 4; ++r)                               \
          fr[r] = __shfl(fsc, lg * 4 + r, 64);                                    \
      _Pragma("unroll") for (int ct = 0; ct < 4; ++ct)                            \
        _Pragma("unroll") for (int r = 0; r < 4; ++r) oacc[ct][r] *= fr[r];       \
      lsum *= fsc;                                                                \
      mrun = mnew;                                                                \
    }                                                                             \
    float rs = 0.f;                                                               \
    _Pragma("unroll") for (int k2 = 0; k2 < 4; ++k2)                              \
      _Pragma("unroll") for (int r = 0; r < 4; ++r) {                             \
        st[k2][r] = exp2f(st[k2][r] - mrun);                                      \
        rs += st[k2][r];                                                          \
      }                                                                           \
    rs += __shfl_xor(rs, 16, 64);                                                 \
    rs += __shfl_xor(rs, 32, 64);                                                 \
    lsum += rs;                                                                   \
    u32x4 ua, ub;                                                                 \
    ua[0] = cvtpk(st[0][0], st[0][1]); ua[1] = cvtpk(st[0][2], st[0][3]);         \
    ua[2] = cvtpk(st[1][0], st[1][1]); ua[3] = cvtpk(st[1][2], st[1][3]);         \
    ub[0] = cvtpk(st[2][0], st[2][1]); ub[1] = cvtpk(st[2][2], st[2][3]);         \
    ub[2] = cvtpk(st[3][0], st[3][1]); ub[3] = cvtpk(st[3][2], st[3][3]);         \
    short8 pa0 = __builtin_bit_cast(short8, ua);                                  \
    short8 pa1 = __builtin_bit_cast(short8, ub);                                  \
    _Pragma("unroll") for (int ct = 0; ct < 4; ++ct) {                            \
      int br = ct * 16 + lr;                                                      \
      short8 bv0 = *(const short8*)&Vs[BUF][(br << 6) +                           \
                                            ((lg * 8) ^ ((br & 7) << 3))];        \
      short8 bv1 = *(const short8*)&Vs[BUF][(br << 6) +                           \
                                            ((32 + lg * 8) ^ ((br & 7) << 3))];   \
      oacc[ct] = __builtin_amdgcn_mfma_f32_16x16x32_bf16(pa0, bv0, oacc[ct], 0, 0, 0); \
      oacc[ct] = __builtin_amdgcn_mfma_f32_16x16x32_bf16(pa1, bv1, oacc[ct], 0, 0, 0); \
    }                                                                             \
    __syncthreads();                                                              \
  }

  ATTN_STAGE(0)
  __syncthreads();
  for (int ii = 0; ii < 16; ++ii) {
    ATTN_TILE(0, 1)
    ATTN_TILE(1, ii < 15)
  }

  float inv = 1.0f / lsum;
  float invr[4];
#pragma unroll
  for (int r = 0; r < 4; ++r) invr[r] = __shfl(inv, lg * 4 + r, 64);
  const int qg0 = qt * 64 + w * 16 + lg * 4;
#pragma unroll
  for (int ct = 0; ct < 4; ++ct) {
    int col = h * 64 + ct * 16 + lr;
#pragma unroll
    for (int r = 0; r < 4; ++r)
      out[((size_t)b * S_LEN + qg0 + r) * D_EMB + col] = oacc[ct][r] * invr[r];
  }
}

extern "C" void kernel_launch(void* const* d_in, const int* in_sizes, int n_in,
                              void* d_out, int out_size, void* d_ws, size_t ws_size,
                              hipStream_t stream) {
  (void)in_sizes; (void)n_in; (void)out_size; (void)ws_size;
  const float* x  = (const float*)d_in[0];
  const float* Wq = (const float*)d_in[1];
  const float* bq = (const float*)d_in[2];
  float* out = (float*)d_out;
  char* ws = (char*)d_ws;
  // workspace layout (38 MB total)
  u16* xb = (u16*)(ws);                               //  8 MB: x bf16 [4096][1024]
  u16* wt = (u16*)(ws + (size_t)8  * 1024 * 1024);    //  6 MB: Wt bf16 [3072][1024]
  u16* qb = (u16*)(ws + (size_t)14 * 1024 * 1024);    //  8 MB: q [B,H,S,Dh] (pre-scaled)
  u16* kb = (u16*)(ws + (size_t)22 * 1024 * 1024);    //  8 MB: k [B,H,S,Dh]
  u16* vb = (u16*)(ws + (size_t)30 * 1024 * 1024);    //  8 MB: Vt [B,H,Dh,S]

  cvt_x_kern <<<4096, 256, 0, stream>>>(x, xb);
  cvt_wt_kern<<<dim3(48, 16), 256, 0, stream>>>(Wq, wt);
  qkv_gemm_kern<<<dim3(32, 24), 256, 0, stream>>>(xb, wt, bq, qb, kb, vb);
  attn_kern  <<<dim3(32, 32), 256, 0, stream>>>(qb, kb, vb, out);
}